// Round 1
// baseline (2015.069 us; speedup 1.0000x reference)
//
#include <hip/hip_runtime.h>

#define N_NODES 110000
#define NUM_USER 60000

// ---------------- degree / CSR build ----------------

__global__ void count_deg_k(const int* __restrict__ dst, int* __restrict__ deg, int E) {
    int i = blockIdx.x * blockDim.x + threadIdx.x;
    if (i < E) atomicAdd(&deg[dst[i]], 1);
}

__global__ void dinv_k(const int* __restrict__ deg, float* __restrict__ dinv, int n) {
    int i = blockIdx.x * blockDim.x + threadIdx.x;
    if (i < n) dinv[i] = rsqrtf((float)(deg[i] + 1));  // +1 = self-loop
}

// single-block exclusive prefix sum over n (~110000) via wave scans (3 barriers/chunk)
__global__ __launch_bounds__(1024) void scan_k(const int* __restrict__ deg,
                                               int* __restrict__ off, int* __restrict__ cur, int n) {
    __shared__ int wsum[16];
    int tid = threadIdx.x, lane = tid & 63, w = tid >> 6;
    int carry = 0;
    for (int base = 0; base < n; base += 1024) {
        int i = base + tid;
        int v = (i < n) ? deg[i] : 0;
        int s = v;
        #pragma unroll
        for (int o = 1; o < 64; o <<= 1) { int t = __shfl_up(s, o); if (lane >= o) s += t; }
        if (lane == 63) wsum[w] = s;
        __syncthreads();
        if (w == 0) {
            int x = (lane < 16) ? wsum[lane] : 0;
            #pragma unroll
            for (int o = 1; o < 16; o <<= 1) { int t = __shfl_up(x, o); if (lane >= o) x += t; }
            if (lane < 16) wsum[lane] = x;
        }
        __syncthreads();
        int woff = (w > 0) ? wsum[w - 1] : 0;
        int ex = carry + woff + s - v;
        if (i < n) { off[i] = ex; cur[i] = ex; }
        int total = wsum[15];
        __syncthreads();
        carry += total;
    }
}

__global__ void fill_k(const int* __restrict__ src, const int* __restrict__ dst,
                       const float* __restrict__ dinv, int* __restrict__ cur,
                       int* __restrict__ idxb, float* __restrict__ coef, int E) {
    int i = blockIdx.x * blockDim.x + threadIdx.x;
    if (i < E) {
        int s = src[i], d = dst[i];
        int p = atomicAdd(&cur[d], 1);
        idxb[p] = s;
        coef[p] = dinv[s] * dinv[d];
    }
}

// ---------------- dense X@W (f32 vector ALU) ----------------
// block: 256 threads, tile 32 rows x 128 cols, thread computes 4x4, W k-chunked in LDS

__global__ __launch_bounds__(256) void matmul_k(const float* __restrict__ X, const float* __restrict__ W,
                                                float* __restrict__ C, int nrows) {
    __shared__ float Ws[64][128];
    int tid = threadIdx.x;
    int tx = tid & 31, ty = tid >> 5;
    int row0 = blockIdx.x * 32 + ty * 4;
    int c = tx * 4;
    float4 acc[4];
    acc[0] = acc[1] = acc[2] = acc[3] = make_float4(0.f, 0.f, 0.f, 0.f);
    bool rv[4];
    #pragma unroll
    for (int i = 0; i < 4; i++) rv[i] = (row0 + i) < nrows;

    for (int kc = 0; kc < 128; kc += 64) {
        __syncthreads();
        for (int t = tid; t < 64 * 32; t += 256) {
            int kr = t >> 5, cq = (t & 31) * 4;
            *(float4*)&Ws[kr][cq] = *(const float4*)&W[(kc + kr) * 128 + cq];
        }
        __syncthreads();
        #pragma unroll 4
        for (int k = 0; k < 64; k += 4) {
            float4 av[4];
            #pragma unroll
            for (int i = 0; i < 4; i++)
                av[i] = rv[i] ? *(const float4*)&X[(row0 + i) * 128 + kc + k]
                              : make_float4(0.f, 0.f, 0.f, 0.f);
            #pragma unroll
            for (int kk = 0; kk < 4; kk++) {
                float4 wv = *(const float4*)&Ws[k + kk][c];
                #pragma unroll
                for (int i = 0; i < 4; i++) {
                    float a = ((const float*)&av[i])[kk];
                    acc[i].x += a * wv.x; acc[i].y += a * wv.y;
                    acc[i].z += a * wv.z; acc[i].w += a * wv.w;
                }
            }
        }
    }
    #pragma unroll
    for (int i = 0; i < 4; i++)
        if (rv[i]) *(float4*)&C[(row0 + i) * 128 + c] = acc[i];
}

// ---------------- sparse aggregate: out[d] = relu(b + dinv[d]^2*T[d] + sum coef*T[src]) ----------------
// one wave per dst node; lane handles 2 feature dims

__global__ __launch_bounds__(64) void aggregate_k(const float* __restrict__ T, const int* __restrict__ idxb,
                                                  const float* __restrict__ coef, const int* __restrict__ off,
                                                  const int* __restrict__ deg, const float* __restrict__ dinv,
                                                  const float* __restrict__ bias, float* __restrict__ out) {
    int d = blockIdx.x;
    int lane = threadIdx.x;
    int k = lane * 2;
    float di = dinv[d];
    float2 t0 = *(const float2*)&T[d * 128 + k];
    float2 acc;
    acc.x = t0.x * di * di;
    acc.y = t0.y * di * di;
    int o = off[d], n = deg[d];
    for (int b0 = 0; b0 < n; b0 += 64) {
        int e = b0 + lane;
        int sv = 0; float cv = 0.f;
        if (e < n) { sv = idxb[o + e]; cv = coef[o + e]; }
        int m = min(64, n - b0);
        for (int j = 0; j < m; j++) {
            int s = __shfl(sv, j);
            float cc = __shfl(cv, j);
            float2 v = *(const float2*)&T[s * 128 + k];
            acc.x += cc * v.x;
            acc.y += cc * v.y;
        }
    }
    acc.x = fmaxf(acc.x + bias[k], 0.f);
    acc.y = fmaxf(acc.y + bias[k + 1], 0.f);
    *(float2*)&out[d * 128 + k] = acc;
}

// ---------------- loss heads ----------------

__device__ __forceinline__ float wred64(float x) {
    #pragma unroll
    for (int o = 32; o > 0; o >>= 1) x += __shfl_xor(x, o);
    return x;
}
// min(softplus(z),100) == -clip(log(sigmoid(-z)),-100)
__device__ __forceinline__ float sp100(float z) {
    float sp = (z > 0.f) ? (z + log1pf(expf(-z))) : log1pf(expf(z));
    return fminf(sp, 100.f);
}

// pass 1: partial dots from layer-1 features
__global__ __launch_bounds__(256) void loss1_k(const float* __restrict__ X1,
        const int* __restrict__ user, const int* __restrict__ item,
        const float* __restrict__ Wp, const float* __restrict__ Wdu, const float* __restrict__ Wdi,
        float* __restrict__ zp, float* __restrict__ zu, float* __restrict__ zi, int B) {
    int lane = threadIdx.x & 63;
    int wid = (blockIdx.x * blockDim.x + threadIdx.x) >> 6;
    int nw = (gridDim.x * blockDim.x) >> 6;
    int k = lane * 2;
    float2 wpu = *(const float2*)&Wp[k];
    float2 wpi = *(const float2*)&Wp[256 + k];
    float2 wdu = *(const float2*)&Wdu[k];
    float2 wdi = *(const float2*)&Wdi[k];
    for (int s = wid; s < B; s += nw) {
        int u = user[s];
        int it = item[s] + NUM_USER;
        float2 uv = *(const float2*)&X1[u * 128 + k];
        float2 iv = *(const float2*)&X1[it * 128 + k];
        float p_ = uv.x * wpu.x + uv.y * wpu.y + iv.x * wpi.x + iv.y * wpi.y;
        float uu = uv.x * wdu.x + uv.y * wdu.y;
        float ii = iv.x * wdi.x + iv.y * wdi.y;
        p_ = wred64(p_); uu = wred64(uu); ii = wred64(ii);
        if (lane == 0) { zp[s] = p_; zu[s] = uu; zi[s] = ii; }
    }
}

// pass 2: finish dots with layer-2 features, BCE, accumulate
__global__ __launch_bounds__(256) void loss2_k(const float* __restrict__ X2,
        const int* __restrict__ user, const int* __restrict__ item, const int* __restrict__ labels,
        const float* __restrict__ Wp, const float* __restrict__ bp,
        const float* __restrict__ Wdu, const float* __restrict__ bdu,
        const float* __restrict__ Wdi, const float* __restrict__ bdi,
        const float* __restrict__ zp, const float* __restrict__ zu, const float* __restrict__ zi,
        float* __restrict__ acc, int is_target, int B) {
    __shared__ float part[3][4];
    int tid = threadIdx.x;
    int lane = tid & 63, w = tid >> 6;
    int wid = (blockIdx.x * blockDim.x + tid) >> 6;
    int nw = (gridDim.x * blockDim.x) >> 6;
    int k = lane * 2;
    float2 wpu = *(const float2*)&Wp[128 + k];
    float2 wpi = *(const float2*)&Wp[384 + k];
    float2 wdu = *(const float2*)&Wdu[128 + k];
    float2 wdi = *(const float2*)&Wdi[128 + k];
    float lp = 0.f, lu = 0.f, li = 0.f;
    for (int s = wid; s < B; s += nw) {
        int u = user[s];
        int it = item[s] + NUM_USER;
        float2 uv = *(const float2*)&X2[u * 128 + k];
        float2 iv = *(const float2*)&X2[it * 128 + k];
        float p_ = uv.x * wpu.x + uv.y * wpu.y + iv.x * wpi.x + iv.y * wpi.y;
        float uu = uv.x * wdu.x + uv.y * wdu.y;
        float ii = iv.x * wdi.x + iv.y * wdi.y;
        p_ = wred64(p_); uu = wred64(uu); ii = wred64(ii);
        if (lane == 0) {
            float zpt = zp[s] + p_ + bp[0];
            float zut = zu[s] + uu + bdu[0];
            float zit = zi[s] + ii + bdi[0];
            lp += labels[s] ? sp100(-zpt) : sp100(zpt);
            lu += is_target ? sp100(-zut) : sp100(zut);
            li += is_target ? sp100(-zit) : sp100(zit);
        }
    }
    if (lane == 0) { part[0][w] = lp; part[1][w] = lu; part[2][w] = li; }
    __syncthreads();
    if (tid == 0) {
        float s0 = 0.f, s1 = 0.f, s2 = 0.f;
        for (int j = 0; j < 4; j++) { s0 += part[0][j]; s1 += part[1][j]; s2 += part[2][j]; }
        atomicAdd(&acc[is_target ? 1 : 0], s0);
        atomicAdd(&acc[2], s1);   // pu sum
        atomicAdd(&acc[3], s2);   // pi sum
    }
}

__global__ void fin_k(const float* __restrict__ acc, float* __restrict__ out, int B) {
    float invB = 1.f / (float)B;
    // loss_s + loss_t + 0.1*(bce_pi_mean + bce_pu_mean), means over 2B
    out[0] = acc[0] * invB + acc[1] * invB + 0.1f * ((acc[2] + acc[3]) * (0.5f * invB));
}

// ---------------- orchestration ----------------

extern "C" void kernel_launch(void* const* d_in, const int* in_sizes, int n_in,
                              void* d_out, int out_size, void* d_ws, size_t ws_size,
                              hipStream_t stream) {
    const float* feats[2] = {(const float*)d_in[0], (const float*)d_in[1]};
    const int* adj[2]    = {(const int*)d_in[2], (const int*)d_in[3]};
    const int* user[2]   = {(const int*)d_in[4], (const int*)d_in[7]};
    const int* item[2]   = {(const int*)d_in[5], (const int*)d_in[8]};
    const int* labels[2] = {(const int*)d_in[6], (const int*)d_in[9]};
    const float* Wl[2] = {(const float*)d_in[10], (const float*)d_in[12]};
    const float* bl[2] = {(const float*)d_in[11], (const float*)d_in[13]};
    const float* Wp  = (const float*)d_in[14];
    const float* bp  = (const float*)d_in[15];
    const float* Wdu = (const float*)d_in[16];
    const float* bdu = (const float*)d_in[17];
    const float* Wdi = (const float*)d_in[18];
    const float* bdi = (const float*)d_in[19];

    const int E = in_sizes[2] / 2;
    const int B = in_sizes[4];
    const int N = N_NODES;

    char* w = (char*)d_ws;
    float* T    = (float*)w; w += (size_t)N * 128 * 4;
    float* A    = (float*)w; w += (size_t)N * 128 * 4;
    int*   deg  = (int*)w;   w += (size_t)N * 4;
    float* dinv = (float*)w; w += (size_t)N * 4;
    int*   off  = (int*)w;   w += (size_t)N * 4;
    int*   cur  = (int*)w;   w += (size_t)N * 4;
    int*   idxb = (int*)w;   w += (size_t)E * 4;
    float* coef = (float*)w; w += (size_t)E * 4;
    float* zp   = (float*)w; w += (size_t)B * 4;
    float* zu   = (float*)w; w += (size_t)B * 4;
    float* zi   = (float*)w; w += (size_t)B * 4;
    float* acc  = (float*)w; w += 64;

    hipMemsetAsync(acc, 0, 4 * sizeof(float), stream);

    int gE = (E + 255) / 256, gN = (N + 255) / 256;
    for (int dom = 0; dom < 2; dom++) {
        const int* srcp = adj[dom];
        const int* dstp = adj[dom] + E;
        hipMemsetAsync(deg, 0, (size_t)N * 4, stream);
        count_deg_k<<<gE, 256, 0, stream>>>(dstp, deg, E);
        dinv_k<<<gN, 256, 0, stream>>>(deg, dinv, N);
        scan_k<<<1, 1024, 0, stream>>>(deg, off, cur, N);
        fill_k<<<gE, 256, 0, stream>>>(srcp, dstp, dinv, cur, idxb, coef, E);

        // layer 1
        matmul_k<<<(N + 31) / 32, 256, 0, stream>>>(feats[dom], Wl[0], T, N);
        aggregate_k<<<N, 64, 0, stream>>>(T, idxb, coef, off, deg, dinv, bl[0], A);
        loss1_k<<<512, 256, 0, stream>>>(A, user[dom], item[dom], Wp, Wdu, Wdi, zp, zu, zi, B);

        // layer 2 (aggregate may overwrite A: matmul already consumed it)
        matmul_k<<<(N + 31) / 32, 256, 0, stream>>>(A, Wl[1], T, N);
        aggregate_k<<<N, 64, 0, stream>>>(T, idxb, coef, off, deg, dinv, bl[1], A);
        loss2_k<<<512, 256, 0, stream>>>(A, user[dom], item[dom], labels[dom],
                                         Wp, bp, Wdu, bdu, Wdi, bdi,
                                         zp, zu, zi, acc, dom, B);
    }
    fin_k<<<1, 1, 0, stream>>>(acc, (float*)d_out, B);
}

// Round 2
// 1700.506 us; speedup vs baseline: 1.1850x; 1.1850x over previous
//
#include <hip/hip_runtime.h>

#define N_NODES 110000
#define NUM_USER 60000
#define MPAD 110016   // N_NODES padded to 64-row GEMM tiles

typedef __attribute__((ext_vector_type(8))) __bf16 bf16x8;
typedef __attribute__((ext_vector_type(4))) float f32x4;
typedef __attribute__((ext_vector_type(4))) unsigned int uint4v;

union UB { uint4v u; bf16x8 b; };

__device__ __forceinline__ unsigned short f2b(float f) {   // f32 -> bf16 RNE
    unsigned int u = __float_as_uint(f);
    unsigned int r = (u + 0x7FFFu + ((u >> 16) & 1u)) >> 16;
    return (unsigned short)r;
}
__device__ __forceinline__ float b2f(unsigned short h) {
    return __uint_as_float(((unsigned int)h) << 16);
}

// ---------------- degree / CSR build ----------------

__global__ void count_deg_k(const int* __restrict__ dst, int* __restrict__ deg, int E) {
    int i = blockIdx.x * blockDim.x + threadIdx.x;
    if (i < E) atomicAdd(&deg[dst[i]], 1);
}

__global__ void dinv_k(const int* __restrict__ deg, float* __restrict__ dinv, int n) {
    int i = blockIdx.x * blockDim.x + threadIdx.x;
    if (i < n) dinv[i] = rsqrtf((float)(deg[i] + 1));  // +1 = self-loop
}

__global__ __launch_bounds__(1024) void scan_k(const int* __restrict__ deg,
                                               int* __restrict__ off, int* __restrict__ cur, int n) {
    __shared__ int wsum[16];
    int tid = threadIdx.x, lane = tid & 63, w = tid >> 6;
    int carry = 0;
    for (int base = 0; base < n; base += 1024) {
        int i = base + tid;
        int v = (i < n) ? deg[i] : 0;
        int s = v;
        #pragma unroll
        for (int o = 1; o < 64; o <<= 1) { int t = __shfl_up(s, o); if (lane >= o) s += t; }
        if (lane == 63) wsum[w] = s;
        __syncthreads();
        if (w == 0) {
            int x = (lane < 16) ? wsum[lane] : 0;
            #pragma unroll
            for (int o = 1; o < 16; o <<= 1) { int t = __shfl_up(x, o); if (lane >= o) x += t; }
            if (lane < 16) wsum[lane] = x;
        }
        __syncthreads();
        int woff = (w > 0) ? wsum[w - 1] : 0;
        int ex = carry + woff + s - v;
        if (i < n) { off[i] = ex; cur[i] = ex; }
        int total = wsum[15];
        __syncthreads();
        carry += total;
    }
}

__global__ void fill_k(const int* __restrict__ src, const int* __restrict__ dst,
                       const float* __restrict__ dinv, int* __restrict__ cur,
                       int* __restrict__ idxb, float* __restrict__ coef, int E) {
    int i = blockIdx.x * blockDim.x + threadIdx.x;
    if (i < E) {
        int s = src[i], d = dst[i];
        int p = atomicAdd(&cur[d], 1);
        idxb[p] = s;
        coef[p] = dinv[s] * dinv[d];
    }
}

// ---------------- f32 -> (hi,lo) bf16 split ----------------

__global__ __launch_bounds__(256) void convx_k(const float* __restrict__ X,
        ushort* __restrict__ hi, ushort* __restrict__ lo, int nelem) {
    int i = blockIdx.x * blockDim.x + threadIdx.x;   // group of 4 floats; grid covers MPAD*128/4
    int i4 = i * 4;
    float f[4] = {0.f, 0.f, 0.f, 0.f};
    if (i4 < nelem) {
        float4 v = *(const float4*)&X[i4];
        f[0] = v.x; f[1] = v.y; f[2] = v.z; f[3] = v.w;
    }
    ushort h[4], l[4];
    #pragma unroll
    for (int j = 0; j < 4; j++) { h[j] = f2b(f[j]); l[j] = f2b(f[j] - b2f(h[j])); }
    *(ushort4*)&hi[i4] = make_ushort4(h[0], h[1], h[2], h[3]);
    *(ushort4*)&lo[i4] = make_ushort4(l[0], l[1], l[2], l[3]);
}

// W (128x128, [k][n]) -> transposed bf16 hi/lo ([n][k])
__global__ __launch_bounds__(256) void convw_k(const float* __restrict__ W,
        ushort* __restrict__ hi, ushort* __restrict__ lo) {
    int i = blockIdx.x * blockDim.x + threadIdx.x;   // 16384 total
    int k = i >> 7, n = i & 127;
    float w = W[i];
    ushort h = f2b(w);
    hi[(n << 7) | k] = h;
    lo[(n << 7) | k] = f2b(w - b2f(h));
}

// ---------------- GEMM: C(f32, Mx128) = (Xhi+Xlo)(Mx128) @ (Whi+Wlo)(128x128) ----------------
// split-bf16: hi*hi + hi*lo + lo*hi via mfma_f32_16x16x32_bf16
// block = 256 threads = 4 waves; wave owns 16 rows x 128 cols (8 n-tiles); grid = MPAD/64

__global__ __launch_bounds__(256) void mm_k(const ushort* __restrict__ Xhi, const ushort* __restrict__ Xlo,
        const ushort* __restrict__ Whi, const ushort* __restrict__ Wlo,   // [n][k] transposed
        float* __restrict__ C, int M) {
    int wid = threadIdx.x >> 6, lane = threadIdx.x & 63;
    int row0 = blockIdx.x * 64 + wid * 16;
    int l15 = lane & 15;
    int rA = row0 + l15;
    int kg = (lane >> 4) * 8;
    f32x4 acc[8] = {};
    #pragma unroll
    for (int g = 0; g < 4; g++) {
        int k0 = g * 32 + kg;
        UB ahi, alo;
        ahi.u = *(const uint4v*)&Xhi[(size_t)rA * 128 + k0];
        alo.u = *(const uint4v*)&Xlo[(size_t)rA * 128 + k0];
        #pragma unroll
        for (int n = 0; n < 8; n++) {
            UB bhi, blo;
            bhi.u = *(const uint4v*)&Whi[(n * 16 + l15) * 128 + k0];
            blo.u = *(const uint4v*)&Wlo[(n * 16 + l15) * 128 + k0];
            acc[n] = __builtin_amdgcn_mfma_f32_16x16x32_bf16(ahi.b, bhi.b, acc[n], 0, 0, 0);
            acc[n] = __builtin_amdgcn_mfma_f32_16x16x32_bf16(ahi.b, blo.b, acc[n], 0, 0, 0);
            acc[n] = __builtin_amdgcn_mfma_f32_16x16x32_bf16(alo.b, bhi.b, acc[n], 0, 0, 0);
        }
    }
    int rbase = row0 + (lane >> 4) * 4;
    #pragma unroll
    for (int r = 0; r < 4; r++) {
        int row = rbase + r;
        if (row < M) {
            #pragma unroll
            for (int n = 0; n < 8; n++)
                C[(size_t)row * 128 + n * 16 + l15] = acc[n][r];
        }
    }
}

// ---------------- sparse aggregate: out[d] = relu(b + dinv[d]^2*T[d] + sum coef*T[src]) ----------------
// one wave per dst node; lane handles 2 feature dims; output written as bf16 hi/lo pair

__global__ __launch_bounds__(64) void aggregate_k(const float* __restrict__ T, const int* __restrict__ idxb,
        const float* __restrict__ coef, const int* __restrict__ off,
        const int* __restrict__ deg, const float* __restrict__ dinv,
        const float* __restrict__ bias, ushort* __restrict__ ohi, ushort* __restrict__ olo, int N) {
    int d = blockIdx.x;
    int lane = threadIdx.x;
    int k = lane * 2;
    if (d >= N) {   // pad rows for GEMM tiles: keep zeroed
        *(ushort2*)&ohi[(size_t)d * 128 + k] = make_ushort2(0, 0);
        *(ushort2*)&olo[(size_t)d * 128 + k] = make_ushort2(0, 0);
        return;
    }
    float di = dinv[d];
    float2 t0 = *(const float2*)&T[(size_t)d * 128 + k];
    float2 acc;
    acc.x = t0.x * di * di;
    acc.y = t0.y * di * di;
    int o = off[d], n = deg[d];
    for (int b0 = 0; b0 < n; b0 += 64) {
        int e = b0 + lane;
        int sv = 0; float cv = 0.f;
        if (e < n) { sv = idxb[o + e]; cv = coef[o + e]; }
        int m = min(64, n - b0);
        for (int j = 0; j < m; j++) {
            int s = __shfl(sv, j);
            float cc = __shfl(cv, j);
            float2 v = *(const float2*)&T[(size_t)s * 128 + k];
            acc.x += cc * v.x;
            acc.y += cc * v.y;
        }
    }
    float ax = fmaxf(acc.x + bias[k], 0.f);
    float ay = fmaxf(acc.y + bias[k + 1], 0.f);
    ushort hx = f2b(ax), hy = f2b(ay);
    *(ushort2*)&ohi[(size_t)d * 128 + k] = make_ushort2(hx, hy);
    *(ushort2*)&olo[(size_t)d * 128 + k] = make_ushort2(f2b(ax - b2f(hx)), f2b(ay - b2f(hy)));
}

// ---------------- loss heads ----------------

__device__ __forceinline__ float wred64(float x) {
    #pragma unroll
    for (int o = 32; o > 0; o >>= 1) x += __shfl_xor(x, o);
    return x;
}
__device__ __forceinline__ float sp100(float z) {   // min(softplus(z),100) == -clip(log(sigmoid(-z)),-100)
    float sp = (z > 0.f) ? (z + log1pf(expf(-z))) : log1pf(expf(z));
    return fminf(sp, 100.f);
}
__device__ __forceinline__ float2 ldf2(const ushort* hi, const ushort* lo, size_t idx) {
    ushort2 h = *(const ushort2*)&hi[idx];
    ushort2 l = *(const ushort2*)&lo[idx];
    float2 r;
    r.x = b2f(h.x) + b2f(l.x);
    r.y = b2f(h.y) + b2f(l.y);
    return r;
}

// pass 1: partial dots from layer-1 features
__global__ __launch_bounds__(256) void loss1_k(const ushort* __restrict__ Xhi, const ushort* __restrict__ Xlo,
        const int* __restrict__ user, const int* __restrict__ item,
        const float* __restrict__ Wp, const float* __restrict__ Wdu, const float* __restrict__ Wdi,
        float* __restrict__ zp, float* __restrict__ zu, float* __restrict__ zi, int B) {
    int lane = threadIdx.x & 63;
    int wid = (blockIdx.x * blockDim.x + threadIdx.x) >> 6;
    int nw = (gridDim.x * blockDim.x) >> 6;
    int k = lane * 2;
    float2 wpu = *(const float2*)&Wp[k];
    float2 wpi = *(const float2*)&Wp[256 + k];
    float2 wdu = *(const float2*)&Wdu[k];
    float2 wdi = *(const float2*)&Wdi[k];
    for (int s = wid; s < B; s += nw) {
        int u = user[s];
        int it = item[s] + NUM_USER;
        float2 uv = ldf2(Xhi, Xlo, (size_t)u * 128 + k);
        float2 iv = ldf2(Xhi, Xlo, (size_t)it * 128 + k);
        float p_ = uv.x * wpu.x + uv.y * wpu.y + iv.x * wpi.x + iv.y * wpi.y;
        float uu = uv.x * wdu.x + uv.y * wdu.y;
        float ii = iv.x * wdi.x + iv.y * wdi.y;
        p_ = wred64(p_); uu = wred64(uu); ii = wred64(ii);
        if (lane == 0) { zp[s] = p_; zu[s] = uu; zi[s] = ii; }
    }
}

// pass 2: finish dots with layer-2 features, BCE, accumulate
__global__ __launch_bounds__(256) void loss2_k(const ushort* __restrict__ Xhi, const ushort* __restrict__ Xlo,
        const int* __restrict__ user, const int* __restrict__ item, const int* __restrict__ labels,
        const float* __restrict__ Wp, const float* __restrict__ bp,
        const float* __restrict__ Wdu, const float* __restrict__ bdu,
        const float* __restrict__ Wdi, const float* __restrict__ bdi,
        const float* __restrict__ zp, const float* __restrict__ zu, const float* __restrict__ zi,
        float* __restrict__ acc, int is_target, int B) {
    __shared__ float part[3][4];
    int tid = threadIdx.x;
    int lane = tid & 63, w = tid >> 6;
    int wid = (blockIdx.x * blockDim.x + tid) >> 6;
    int nw = (gridDim.x * blockDim.x) >> 6;
    int k = lane * 2;
    float2 wpu = *(const float2*)&Wp[128 + k];
    float2 wpi = *(const float2*)&Wp[384 + k];
    float2 wdu = *(const float2*)&Wdu[128 + k];
    float2 wdi = *(const float2*)&Wdi[128 + k];
    float lp = 0.f, lu = 0.f, li = 0.f;
    for (int s = wid; s < B; s += nw) {
        int u = user[s];
        int it = item[s] + NUM_USER;
        float2 uv = ldf2(Xhi, Xlo, (size_t)u * 128 + k);
        float2 iv = ldf2(Xhi, Xlo, (size_t)it * 128 + k);
        float p_ = uv.x * wpu.x + uv.y * wpu.y + iv.x * wpi.x + iv.y * wpi.y;
        float uu = uv.x * wdu.x + uv.y * wdu.y;
        float ii = iv.x * wdi.x + iv.y * wdi.y;
        p_ = wred64(p_); uu = wred64(uu); ii = wred64(ii);
        if (lane == 0) {
            float zpt = zp[s] + p_ + bp[0];
            float zut = zu[s] + uu + bdu[0];
            float zit = zi[s] + ii + bdi[0];
            lp += labels[s] ? sp100(-zpt) : sp100(zpt);
            lu += is_target ? sp100(-zut) : sp100(zut);
            li += is_target ? sp100(-zit) : sp100(zit);
        }
    }
    if (lane == 0) { part[0][w] = lp; part[1][w] = lu; part[2][w] = li; }
    __syncthreads();
    if (tid == 0) {
        float s0 = 0.f, s1 = 0.f, s2 = 0.f;
        for (int j = 0; j < 4; j++) { s0 += part[0][j]; s1 += part[1][j]; s2 += part[2][j]; }
        atomicAdd(&acc[is_target ? 1 : 0], s0);
        atomicAdd(&acc[2], s1);
        atomicAdd(&acc[3], s2);
    }
}

__global__ void fin_k(const float* __restrict__ acc, float* __restrict__ out, int B) {
    float invB = 1.f / (float)B;
    out[0] = acc[0] * invB + acc[1] * invB + 0.1f * ((acc[2] + acc[3]) * (0.5f * invB));
}

// ---------------- orchestration ----------------

extern "C" void kernel_launch(void* const* d_in, const int* in_sizes, int n_in,
                              void* d_out, int out_size, void* d_ws, size_t ws_size,
                              hipStream_t stream) {
    const float* feats[2] = {(const float*)d_in[0], (const float*)d_in[1]};
    const int* adj[2]    = {(const int*)d_in[2], (const int*)d_in[3]};
    const int* user[2]   = {(const int*)d_in[4], (const int*)d_in[7]};
    const int* item[2]   = {(const int*)d_in[5], (const int*)d_in[8]};
    const int* labels[2] = {(const int*)d_in[6], (const int*)d_in[9]};
    const float* Wl[2] = {(const float*)d_in[10], (const float*)d_in[12]};
    const float* bl[2] = {(const float*)d_in[11], (const float*)d_in[13]};
    const float* Wp  = (const float*)d_in[14];
    const float* bp  = (const float*)d_in[15];
    const float* Wdu = (const float*)d_in[16];
    const float* bdu = (const float*)d_in[17];
    const float* Wdi = (const float*)d_in[18];
    const float* bdi = (const float*)d_in[19];

    const int E = in_sizes[2] / 2;
    const int B = in_sizes[4];
    const int N = N_NODES;

    char* w = (char*)d_ws;
    float*  T    = (float*)w;  w += (size_t)N * 128 * 4;
    ushort* Fhi  = (ushort*)w; w += (size_t)MPAD * 128 * 2;   // X hi for layer-1, A hi after aggregate
    ushort* Flo  = (ushort*)w; w += (size_t)MPAD * 128 * 2;
    ushort* W1h  = (ushort*)w; w += 16384 * 2;
    ushort* W1l  = (ushort*)w; w += 16384 * 2;
    ushort* W2h  = (ushort*)w; w += 16384 * 2;
    ushort* W2l  = (ushort*)w; w += 16384 * 2;
    int*   deg  = (int*)w;   w += (size_t)N * 4;
    float* dinv = (float*)w; w += (size_t)N * 4;
    int*   off  = (int*)w;   w += (size_t)N * 4;
    int*   cur  = (int*)w;   w += (size_t)N * 4;
    int*   idxb = (int*)w;   w += (size_t)E * 4;
    float* coef = (float*)w; w += (size_t)E * 4;
    float* zp   = (float*)w; w += (size_t)B * 4;
    float* zu   = (float*)w; w += (size_t)B * 4;
    float* zi   = (float*)w; w += (size_t)B * 4;
    float* acc  = (float*)w; w += 64;

    hipMemsetAsync(acc, 0, 4 * sizeof(float), stream);
    convw_k<<<64, 256, 0, stream>>>(Wl[0], W1h, W1l);
    convw_k<<<64, 256, 0, stream>>>(Wl[1], W2h, W2l);

    int gE = (E + 255) / 256, gN = (N + 255) / 256;
    int gConv = (MPAD * 128 / 4 + 255) / 256;
    int gMM = MPAD / 64;
    for (int dom = 0; dom < 2; dom++) {
        const int* srcp = adj[dom];
        const int* dstp = adj[dom] + E;
        hipMemsetAsync(deg, 0, (size_t)N * 4, stream);
        count_deg_k<<<gE, 256, 0, stream>>>(dstp, deg, E);
        dinv_k<<<gN, 256, 0, stream>>>(deg, dinv, N);
        scan_k<<<1, 1024, 0, stream>>>(deg, off, cur, N);
        fill_k<<<gE, 256, 0, stream>>>(srcp, dstp, dinv, cur, idxb, coef, E);

        // layer 1
        convx_k<<<gConv, 256, 0, stream>>>(feats[dom], Fhi, Flo, N * 128);
        mm_k<<<gMM, 256, 0, stream>>>(Fhi, Flo, W1h, W1l, T, N);
        aggregate_k<<<MPAD, 64, 0, stream>>>(T, idxb, coef, off, deg, dinv, bl[0], Fhi, Flo, N);
        loss1_k<<<512, 256, 0, stream>>>(Fhi, Flo, user[dom], item[dom], Wp, Wdu, Wdi, zp, zu, zi, B);

        // layer 2
        mm_k<<<gMM, 256, 0, stream>>>(Fhi, Flo, W2h, W2l, T, N);
        aggregate_k<<<MPAD, 64, 0, stream>>>(T, idxb, coef, off, deg, dinv, bl[1], Fhi, Flo, N);
        loss2_k<<<512, 256, 0, stream>>>(Fhi, Flo, user[dom], item[dom], labels[dom],
                                         Wp, bp, Wdu, bdu, Wdi, bdi,
                                         zp, zu, zi, acc, dom, B);
    }
    fin_k<<<1, 1, 0, stream>>>(acc, (float*)d_out, B);
}

// Round 3
// 1375.286 us; speedup vs baseline: 1.4652x; 1.2365x over previous
//
#include <hip/hip_runtime.h>

#define N_NODES 110000
#define NUM_USER 60000
#define MPAD 110016   // N_NODES padded to 64-row GEMM tiles

typedef __attribute__((ext_vector_type(8))) __bf16 bf16x8;
typedef __attribute__((ext_vector_type(4))) float f32x4;
typedef __attribute__((ext_vector_type(4))) unsigned int uint4v;

union UB { uint4v u; bf16x8 b; };

__device__ __forceinline__ unsigned short f2b(float f) {   // f32 -> bf16 RNE
    unsigned int u = __float_as_uint(f);
    unsigned int r = (u + 0x7FFFu + ((u >> 16) & 1u)) >> 16;
    return (unsigned short)r;
}
__device__ __forceinline__ float b2f(unsigned short h) {
    return __uint_as_float(((unsigned int)h) << 16);
}

// ---------------- degree / CSR build ----------------

__global__ void count_deg_k(const int* __restrict__ dst, int* __restrict__ deg, int E) {
    int i4 = (blockIdx.x * blockDim.x + threadIdx.x) * 4;
    if (i4 + 3 < E) {
        int4 d = *(const int4*)&dst[i4];
        atomicAdd(&deg[d.x], 1); atomicAdd(&deg[d.y], 1);
        atomicAdd(&deg[d.z], 1); atomicAdd(&deg[d.w], 1);
    } else {
        for (int i = i4; i < E; i++) atomicAdd(&deg[dst[i]], 1);
    }
}

// dinv + segment offsets via atomic bump (segment order arbitrary; each segment contiguous)
__global__ void dinv_off_k(const int* __restrict__ deg, float* __restrict__ dinv,
                           int* __restrict__ off, int* __restrict__ cur,
                           int* __restrict__ total, int n) {
    int i = blockIdx.x * blockDim.x + threadIdx.x;
    if (i < n) {
        int dg = deg[i];
        dinv[i] = rsqrtf((float)(dg + 1));  // +1 = self-loop
        int o = atomicAdd(total, dg);
        off[i] = o;
        cur[i] = o;
    }
}

__global__ void fill_k(const int* __restrict__ src, const int* __restrict__ dst,
                       int* __restrict__ cur, int* __restrict__ idxb, int E) {
    int i4 = (blockIdx.x * blockDim.x + threadIdx.x) * 4;
    if (i4 + 3 < E) {
        int4 s = *(const int4*)&src[i4];
        int4 d = *(const int4*)&dst[i4];
        idxb[atomicAdd(&cur[d.x], 1)] = s.x;
        idxb[atomicAdd(&cur[d.y], 1)] = s.y;
        idxb[atomicAdd(&cur[d.z], 1)] = s.z;
        idxb[atomicAdd(&cur[d.w], 1)] = s.w;
    } else {
        for (int i = i4; i < E; i++) idxb[atomicAdd(&cur[dst[i]], 1)] = src[i];
    }
}

// W (128x128, [k][n]) -> transposed bf16 hi/lo ([n][k])
__global__ __launch_bounds__(256) void convw_k(const float* __restrict__ W,
        ushort* __restrict__ hi, ushort* __restrict__ lo) {
    int i = blockIdx.x * blockDim.x + threadIdx.x;   // 16384 total
    int k = i >> 7, n = i & 127;
    float w = W[i];
    ushort h = f2b(w);
    hi[(n << 7) | k] = h;
    lo[(n << 7) | k] = f2b(w - b2f(h));
}

// ---------------- GEMM: T'(bf16, Mx128) = dinv[row] * (A @ W), split-bf16 MFMA ----------------
// A is f32 (layer 1 input feats) or bf16 hi/lo (aggregate output). hi*hi + hi*lo + lo*hi.
// block = 256 = 4 waves; wave owns 16 rows x 128 cols; grid = MPAD/64

template<bool F32A>
__global__ __launch_bounds__(256) void mm_k(const float* __restrict__ Xf,
        const ushort* __restrict__ Xhi, const ushort* __restrict__ Xlo,
        const ushort* __restrict__ Whi, const ushort* __restrict__ Wlo,   // [n][k]
        const float* __restrict__ dinv, ushort* __restrict__ Tp, int M) {
    int wid = threadIdx.x >> 6, lane = threadIdx.x & 63;
    int row0 = blockIdx.x * 64 + wid * 16;
    int l15 = lane & 15;
    int rA = row0 + l15;
    int kg = (lane >> 4) * 8;
    f32x4 acc[8] = {};
    #pragma unroll
    for (int g = 0; g < 4; g++) {
        int k0 = g * 32 + kg;
        UB ahi, alo;
        if (F32A) {
            float4 f0 = make_float4(0.f, 0.f, 0.f, 0.f), f1 = f0;
            if (rA < M) {
                f0 = *(const float4*)&Xf[(size_t)rA * 128 + k0];
                f1 = *(const float4*)&Xf[(size_t)rA * 128 + k0 + 4];
            }
            float f[8] = {f0.x, f0.y, f0.z, f0.w, f1.x, f1.y, f1.z, f1.w};
            ushort h[8], l[8];
            #pragma unroll
            for (int j = 0; j < 8; j++) { h[j] = f2b(f[j]); l[j] = f2b(f[j] - b2f(h[j])); }
            ahi.u = uint4v{(uint)h[0] | ((uint)h[1] << 16), (uint)h[2] | ((uint)h[3] << 16),
                           (uint)h[4] | ((uint)h[5] << 16), (uint)h[6] | ((uint)h[7] << 16)};
            alo.u = uint4v{(uint)l[0] | ((uint)l[1] << 16), (uint)l[2] | ((uint)l[3] << 16),
                           (uint)l[4] | ((uint)l[5] << 16), (uint)l[6] | ((uint)l[7] << 16)};
        } else {
            ahi.u = *(const uint4v*)&Xhi[(size_t)rA * 128 + k0];
            alo.u = *(const uint4v*)&Xlo[(size_t)rA * 128 + k0];
        }
        #pragma unroll
        for (int n = 0; n < 8; n++) {
            UB bhi, blo;
            bhi.u = *(const uint4v*)&Whi[(n * 16 + l15) * 128 + k0];
            blo.u = *(const uint4v*)&Wlo[(n * 16 + l15) * 128 + k0];
            acc[n] = __builtin_amdgcn_mfma_f32_16x16x32_bf16(ahi.b, bhi.b, acc[n], 0, 0, 0);
            acc[n] = __builtin_amdgcn_mfma_f32_16x16x32_bf16(ahi.b, blo.b, acc[n], 0, 0, 0);
            acc[n] = __builtin_amdgcn_mfma_f32_16x16x32_bf16(alo.b, bhi.b, acc[n], 0, 0, 0);
        }
    }
    int rbase = row0 + (lane >> 4) * 4;
    #pragma unroll
    for (int r = 0; r < 4; r++) {
        int row = rbase + r;
        if (row < M) {
            float dv = dinv[row];
            #pragma unroll
            for (int n = 0; n < 8; n++)
                Tp[(size_t)row * 128 + n * 16 + l15] = f2b(dv * acc[n][r]);
        }
    }
}

// ---------------- aggregate: out[d] = relu(b + dinv[d]*(T'[d] + sum T'[src])), split hi/lo ----------
// 4 waves/block, one dst per wave; lanes split into two 32-lane groups over alternating edges

__global__ __launch_bounds__(256) void aggregate_k(const ushort* __restrict__ Tp,
        const int* __restrict__ idxb, const int* __restrict__ off, const int* __restrict__ deg,
        const float* __restrict__ dinv, const float* __restrict__ bias,
        ushort* __restrict__ ohi, ushort* __restrict__ olo, int N) {
    int w = threadIdx.x >> 6, lane = threadIdx.x & 63;
    int d = blockIdx.x * 4 + w;
    int half = lane >> 5, l31 = lane & 31;
    int dim4 = l31 * 4;
    if (d >= N) {   // pad rows: zero (GEMM A-operand reads them)
        if (half == 0) *(ushort4*)&ohi[(size_t)d * 128 + dim4] = make_ushort4(0, 0, 0, 0);
        else           *(ushort4*)&olo[(size_t)d * 128 + dim4] = make_ushort4(0, 0, 0, 0);
        return;
    }
    float a0 = 0.f, a1 = 0.f, a2 = 0.f, a3 = 0.f;
    int o = off[d], n = deg[d];
    int cnt = n + 1;   // position 0 = self
    for (int c = 0; c < cnt; c += 64) {
        int p = c + lane;
        int id = 0;
        if (p < cnt) id = (p == 0) ? d : idxb[o + p - 1];
        int m = min(64, cnt - c);
        for (int jj = 0; jj * 2 + half < m; jj++) {
            int s = __shfl(id, jj * 2 + half);
            ushort4 v = *(const ushort4*)&Tp[(size_t)s * 128 + dim4];
            a0 += b2f(v.x); a1 += b2f(v.y); a2 += b2f(v.z); a3 += b2f(v.w);
        }
    }
    a0 += __shfl_xor(a0, 32); a1 += __shfl_xor(a1, 32);
    a2 += __shfl_xor(a2, 32); a3 += __shfl_xor(a3, 32);
    float di = dinv[d];
    float4 bv = *(const float4*)&bias[dim4];
    float f0 = fmaxf(di * a0 + bv.x, 0.f);
    float f1 = fmaxf(di * a1 + bv.y, 0.f);
    float f2 = fmaxf(di * a2 + bv.z, 0.f);
    float f3 = fmaxf(di * a3 + bv.w, 0.f);
    ushort h0 = f2b(f0), h1 = f2b(f1), h2 = f2b(f2), h3 = f2b(f3);
    if (half == 0) {
        *(ushort4*)&ohi[(size_t)d * 128 + dim4] = make_ushort4(h0, h1, h2, h3);
    } else {
        *(ushort4*)&olo[(size_t)d * 128 + dim4] =
            make_ushort4(f2b(f0 - b2f(h0)), f2b(f1 - b2f(h1)), f2b(f2 - b2f(h2)), f2b(f3 - b2f(h3)));
    }
}

// ---------------- loss heads ----------------

__device__ __forceinline__ float wred64(float x) {
    #pragma unroll
    for (int o = 32; o > 0; o >>= 1) x += __shfl_xor(x, o);
    return x;
}
__device__ __forceinline__ float sp100(float z) {   // min(softplus(z),100)
    float sp = (z > 0.f) ? (z + log1pf(expf(-z))) : log1pf(expf(z));
    return fminf(sp, 100.f);
}
__device__ __forceinline__ float2 ldf2(const ushort* hi, const ushort* lo, size_t idx) {
    ushort2 h = *(const ushort2*)&hi[idx];
    ushort2 l = *(const ushort2*)&lo[idx];
    float2 r;
    r.x = b2f(h.x) + b2f(l.x);
    r.y = b2f(h.y) + b2f(l.y);
    return r;
}

__global__ __launch_bounds__(256) void loss1_k(const ushort* __restrict__ Xhi, const ushort* __restrict__ Xlo,
        const int* __restrict__ user, const int* __restrict__ item,
        const float* __restrict__ Wp, const float* __restrict__ Wdu, const float* __restrict__ Wdi,
        float* __restrict__ zp, float* __restrict__ zu, float* __restrict__ zi, int B) {
    int lane = threadIdx.x & 63;
    int wid = (blockIdx.x * blockDim.x + threadIdx.x) >> 6;
    int nw = (gridDim.x * blockDim.x) >> 6;
    int k = lane * 2;
    float2 wpu = *(const float2*)&Wp[k];
    float2 wpi = *(const float2*)&Wp[256 + k];
    float2 wdu = *(const float2*)&Wdu[k];
    float2 wdi = *(const float2*)&Wdi[k];
    for (int s = wid; s < B; s += nw) {
        int u = user[s];
        int it = item[s] + NUM_USER;
        float2 uv = ldf2(Xhi, Xlo, (size_t)u * 128 + k);
        float2 iv = ldf2(Xhi, Xlo, (size_t)it * 128 + k);
        float p_ = uv.x * wpu.x + uv.y * wpu.y + iv.x * wpi.x + iv.y * wpi.y;
        float uu = uv.x * wdu.x + uv.y * wdu.y;
        float ii = iv.x * wdi.x + iv.y * wdi.y;
        p_ = wred64(p_); uu = wred64(uu); ii = wred64(ii);
        if (lane == 0) { zp[s] = p_; zu[s] = uu; zi[s] = ii; }
    }
}

__global__ __launch_bounds__(256) void loss2_k(const ushort* __restrict__ Xhi, const ushort* __restrict__ Xlo,
        const int* __restrict__ user, const int* __restrict__ item, const int* __restrict__ labels,
        const float* __restrict__ Wp, const float* __restrict__ bp,
        const float* __restrict__ Wdu, const float* __restrict__ bdu,
        const float* __restrict__ Wdi, const float* __restrict__ bdi,
        const float* __restrict__ zp, const float* __restrict__ zu, const float* __restrict__ zi,
        float* __restrict__ acc, int is_target, int B) {
    __shared__ float part[3][4];
    int tid = threadIdx.x;
    int lane = tid & 63, w = tid >> 6;
    int wid = (blockIdx.x * blockDim.x + tid) >> 6;
    int nw = (gridDim.x * blockDim.x) >> 6;
    int k = lane * 2;
    float2 wpu = *(const float2*)&Wp[128 + k];
    float2 wpi = *(const float2*)&Wp[384 + k];
    float2 wdu = *(const float2*)&Wdu[128 + k];
    float2 wdi = *(const float2*)&Wdi[128 + k];
    float lp = 0.f, lu = 0.f, li = 0.f;
    for (int s = wid; s < B; s += nw) {
        int u = user[s];
        int it = item[s] + NUM_USER;
        float2 uv = ldf2(Xhi, Xlo, (size_t)u * 128 + k);
        float2 iv = ldf2(Xhi, Xlo, (size_t)it * 128 + k);
        float p_ = uv.x * wpu.x + uv.y * wpu.y + iv.x * wpi.x + iv.y * wpi.y;
        float uu = uv.x * wdu.x + uv.y * wdu.y;
        float ii = iv.x * wdi.x + iv.y * wdi.y;
        p_ = wred64(p_); uu = wred64(uu); ii = wred64(ii);
        if (lane == 0) {
            float zpt = zp[s] + p_ + bp[0];
            float zut = zu[s] + uu + bdu[0];
            float zit = zi[s] + ii + bdi[0];
            lp += labels[s] ? sp100(-zpt) : sp100(zpt);
            lu += is_target ? sp100(-zut) : sp100(zut);
            li += is_target ? sp100(-zit) : sp100(zit);
        }
    }
    if (lane == 0) { part[0][w] = lp; part[1][w] = lu; part[2][w] = li; }
    __syncthreads();
    if (tid == 0) {
        float s0 = 0.f, s1 = 0.f, s2 = 0.f;
        for (int j = 0; j < 4; j++) { s0 += part[0][j]; s1 += part[1][j]; s2 += part[2][j]; }
        atomicAdd(&acc[is_target ? 1 : 0], s0);
        atomicAdd(&acc[2], s1);
        atomicAdd(&acc[3], s2);
    }
}

__global__ void fin_k(const float* __restrict__ acc, float* __restrict__ out, int B) {
    float invB = 1.f / (float)B;
    out[0] = acc[0] * invB + acc[1] * invB + 0.1f * ((acc[2] + acc[3]) * (0.5f * invB));
}

// ---------------- orchestration ----------------

extern "C" void kernel_launch(void* const* d_in, const int* in_sizes, int n_in,
                              void* d_out, int out_size, void* d_ws, size_t ws_size,
                              hipStream_t stream) {
    const float* feats[2] = {(const float*)d_in[0], (const float*)d_in[1]};
    const int* adj[2]    = {(const int*)d_in[2], (const int*)d_in[3]};
    const int* user[2]   = {(const int*)d_in[4], (const int*)d_in[7]};
    const int* item[2]   = {(const int*)d_in[5], (const int*)d_in[8]};
    const int* labels[2] = {(const int*)d_in[6], (const int*)d_in[9]};
    const float* Wl[2] = {(const float*)d_in[10], (const float*)d_in[12]};
    const float* bl[2] = {(const float*)d_in[11], (const float*)d_in[13]};
    const float* Wp  = (const float*)d_in[14];
    const float* bp  = (const float*)d_in[15];
    const float* Wdu = (const float*)d_in[16];
    const float* bdu = (const float*)d_in[17];
    const float* Wdi = (const float*)d_in[18];
    const float* bdi = (const float*)d_in[19];

    const int E = in_sizes[2] / 2;
    const int B = in_sizes[4];
    const int N = N_NODES;

    char* w = (char*)d_ws;
    ushort* Tp   = (ushort*)w; w += (size_t)MPAD * 128 * 2;
    ushort* Fhi  = (ushort*)w; w += (size_t)MPAD * 128 * 2;
    ushort* Flo  = (ushort*)w; w += (size_t)MPAD * 128 * 2;
    ushort* W1h  = (ushort*)w; w += 16384 * 2;
    ushort* W1l  = (ushort*)w; w += 16384 * 2;
    ushort* W2h  = (ushort*)w; w += 16384 * 2;
    ushort* W2l  = (ushort*)w; w += 16384 * 2;
    int*   deg  = (int*)w;   w += (size_t)N * 4;
    float* dinv = (float*)w; w += (size_t)N * 4;
    int*   off  = (int*)w;   w += (size_t)N * 4;
    int*   cur  = (int*)w;   w += (size_t)N * 4;
    int*   idxb = (int*)w;   w += (size_t)E * 4;
    float* zp   = (float*)w; w += (size_t)B * 4;
    float* zu   = (float*)w; w += (size_t)B * 4;
    float* zi   = (float*)w; w += (size_t)B * 4;
    float* acc  = (float*)w; w += 64;   // [0..3] loss sums, [8..9] total counters

    hipMemsetAsync(acc, 0, 64, stream);
    int* totals = (int*)(acc + 8);
    convw_k<<<64, 256, 0, stream>>>(Wl[0], W1h, W1l);
    convw_k<<<64, 256, 0, stream>>>(Wl[1], W2h, W2l);

    int gE4 = (E / 4 + 255) / 256, gN = (N + 255) / 256;
    int gMM = MPAD / 64, gAG = MPAD / 4;
    for (int dom = 0; dom < 2; dom++) {
        const int* srcp = adj[dom];
        const int* dstp = adj[dom] + E;
        hipMemsetAsync(deg, 0, (size_t)N * 4, stream);
        count_deg_k<<<gE4, 256, 0, stream>>>(dstp, deg, E);
        dinv_off_k<<<gN, 256, 0, stream>>>(deg, dinv, off, cur, &totals[dom], N);
        fill_k<<<gE4, 256, 0, stream>>>(srcp, dstp, cur, idxb, E);

        // layer 1 (f32 input feats, split in-register)
        mm_k<true><<<gMM, 256, 0, stream>>>(feats[dom], nullptr, nullptr, W1h, W1l, dinv, Tp, N);
        aggregate_k<<<gAG, 256, 0, stream>>>(Tp, idxb, off, deg, dinv, bl[0], Fhi, Flo, N);
        loss1_k<<<512, 256, 0, stream>>>(Fhi, Flo, user[dom], item[dom], Wp, Wdu, Wdi, zp, zu, zi, B);

        // layer 2 (bf16 hi/lo input)
        mm_k<false><<<gMM, 256, 0, stream>>>(nullptr, Fhi, Flo, W2h, W2l, dinv, Tp, N);
        aggregate_k<<<gAG, 256, 0, stream>>>(Tp, idxb, off, deg, dinv, bl[1], Fhi, Flo, N);
        loss2_k<<<512, 256, 0, stream>>>(Fhi, Flo, user[dom], item[dom], labels[dom],
                                         Wp, bp, Wdu, bdu, Wdi, bdi,
                                         zp, zu, zi, acc, dom, B);
    }
    fin_k<<<1, 1, 0, stream>>>(acc, (float*)d_out, B);
}

// Round 4
// 1063.692 us; speedup vs baseline: 1.8944x; 1.2929x over previous
//
#include <hip/hip_runtime.h>

#define N_NODES 110000
#define NUM_USER 60000
#define MPAD 110016        // N_NODES padded to 64-row GEMM tiles
#define BSHIFT 9           // bucket = dst >> 9  (512 nodes per bucket)
#define NBUCK 256
#define NPB 512            // nodes per bucket
#define EPB 8192           // edges per block in hist/bin
#define CAP 9216           // per-bucket edge capacity in csr_k LDS (mean 7442, sigma 86)

typedef __attribute__((ext_vector_type(8))) __bf16 bf16x8;
typedef __attribute__((ext_vector_type(4))) float f32x4;
typedef __attribute__((ext_vector_type(4))) unsigned int uint4v;

union UB { uint4v u; bf16x8 b; };

__device__ __forceinline__ unsigned short f2b(float f) {   // f32 -> bf16 RNE
    unsigned int u = __float_as_uint(f);
    unsigned int r = (u + 0x7FFFu + ((u >> 16) & 1u)) >> 16;
    return (unsigned short)r;
}
__device__ __forceinline__ float b2f(unsigned short h) {
    return __uint_as_float(((unsigned int)h) << 16);
}

// ---------------- bucket-sort CSR build ----------------

// per-block histogram of dst>>BSHIFT -> tbl[block][bucket]
__global__ __launch_bounds__(256) void hist_k(const int* __restrict__ dst, int* __restrict__ tbl, int E) {
    __shared__ int h[NBUCK];
    int tid = threadIdx.x, b = blockIdx.x;
    h[tid] = 0;
    __syncthreads();
    int base = b * EPB, end = min(base + EPB, E);
    for (int i = base + tid * 4; i + 3 < end; i += 1024) {
        int4 d = *(const int4*)&dst[i];
        atomicAdd(&h[d.x >> BSHIFT], 1); atomicAdd(&h[d.y >> BSHIFT], 1);
        atomicAdd(&h[d.z >> BSHIFT], 1); atomicAdd(&h[d.w >> BSHIFT], 1);
    }
    __syncthreads();
    tbl[b * NBUCK + tid] = h[tid];
}

// column scan: tbl[blk][t] -> exclusive per-block offset; bucket totals + exclusive bucket bases
__global__ __launch_bounds__(256) void scanb_k(int* __restrict__ tbl, int* __restrict__ bbase,
                                               int* __restrict__ bcnt, int nblocks) {
    __shared__ int sh[NBUCK];
    int t = threadIdx.x;
    int s = 0;
    for (int blk = 0; blk < nblocks; blk++) {
        int v = tbl[blk * NBUCK + t];
        tbl[blk * NBUCK + t] = s;
        s += v;
    }
    bcnt[t] = s;
    sh[t] = s;
    __syncthreads();
    for (int o = 1; o < NBUCK; o <<= 1) {
        int v = (t >= o) ? sh[t - o] : 0;
        __syncthreads();
        sh[t] += v;
        __syncthreads();
    }
    bbase[t] = sh[t] - s;   // exclusive
}

// scatter edges into bucket-major staging; each (block,bucket) run is contiguous
__global__ __launch_bounds__(256) void bin_k(const int* __restrict__ src, const int* __restrict__ dst,
        const int* __restrict__ tbl, const int* __restrict__ bbase,
        unsigned int* __restrict__ stg, int E) {
    __shared__ int lcur[NBUCK];
    int tid = threadIdx.x, b = blockIdx.x;
    lcur[tid] = bbase[tid] + tbl[b * NBUCK + tid];
    __syncthreads();
    int base = b * EPB, end = min(base + EPB, E);
    for (int i = base + tid * 4; i + 3 < end; i += 1024) {
        int4 s = *(const int4*)&src[i];
        int4 d = *(const int4*)&dst[i];
        int p;
        p = atomicAdd(&lcur[d.x >> BSHIFT], 1); stg[p] = (unsigned)s.x | ((unsigned)(d.x & (NPB - 1)) << 17);
        p = atomicAdd(&lcur[d.y >> BSHIFT], 1); stg[p] = (unsigned)s.y | ((unsigned)(d.y & (NPB - 1)) << 17);
        p = atomicAdd(&lcur[d.z >> BSHIFT], 1); stg[p] = (unsigned)s.z | ((unsigned)(d.z & (NPB - 1)) << 17);
        p = atomicAdd(&lcur[d.w >> BSHIFT], 1); stg[p] = (unsigned)s.w | ((unsigned)(d.w & (NPB - 1)) << 17);
    }
}

// per-bucket: LDS histogram -> deg/dinv/off, LDS scatter -> coalesced idxb write
__global__ __launch_bounds__(256) void csr_k(const unsigned int* __restrict__ stg,
        const int* __restrict__ bbase, const int* __restrict__ bcnt,
        int* __restrict__ deg, float* __restrict__ dinv, int* __restrict__ off,
        int* __restrict__ idxb, int N) {
    __shared__ int ldeg[NPB];
    __shared__ int lcur[NPB];
    __shared__ int shp[256];
    __shared__ unsigned int lidx[CAP];
    int tid = threadIdx.x, b = blockIdx.x;
    int node0 = b * NPB;
    int base = bbase[b], cnt = bcnt[b];
    ldeg[tid] = 0; ldeg[tid + 256] = 0;
    __syncthreads();
    for (int i = tid; i < cnt; i += 256)
        atomicAdd(&ldeg[stg[base + i] >> 17], 1);
    __syncthreads();
    int a0 = ldeg[2 * tid], a1 = ldeg[2 * tid + 1];
    shp[tid] = a0 + a1;
    __syncthreads();
    for (int o = 1; o < 256; o <<= 1) {
        int v = (tid >= o) ? shp[tid - o] : 0;
        __syncthreads();
        shp[tid] += v;
        __syncthreads();
    }
    int excl = shp[tid] - a0 - a1;
    lcur[2 * tid] = excl;
    lcur[2 * tid + 1] = excl + a0;
    int n0 = node0 + 2 * tid;
    if (n0 < N)     { deg[n0] = a0;     dinv[n0] = rsqrtf(a0 + 1.f);     off[n0] = base + excl; }
    if (n0 + 1 < N) { deg[n0 + 1] = a1; dinv[n0 + 1] = rsqrtf(a1 + 1.f); off[n0 + 1] = base + excl + a0; }
    __syncthreads();
    for (int i = tid; i < cnt; i += 256) {
        unsigned e = stg[base + i];
        int p = atomicAdd(&lcur[e >> 17], 1);
        if (p < CAP) lidx[p] = e & 0x1FFFFu;
    }
    __syncthreads();
    for (int i = tid; i < cnt; i += 256)
        idxb[base + i] = (int)lidx[i];
}

// ---------------- weights: W (128x128, [k][n]) -> transposed bf16 hi/lo ([n][k]) ----------------

__global__ __launch_bounds__(256) void convw_k(const float* __restrict__ W,
        ushort* __restrict__ hi, ushort* __restrict__ lo) {
    int i = blockIdx.x * blockDim.x + threadIdx.x;   // 16384 total
    int k = i >> 7, n = i & 127;
    float w = W[i];
    ushort h = f2b(w);
    hi[(n << 7) | k] = h;
    lo[(n << 7) | k] = f2b(w - b2f(h));
}

// ---------------- GEMM: T'(bf16, Mx128) = dinv[row] * (A @ W), split-bf16 MFMA ----------------

template<bool F32A>
__global__ __launch_bounds__(256) void mm_k(const float* __restrict__ Xf,
        const ushort* __restrict__ Xhi, const ushort* __restrict__ Xlo,
        const ushort* __restrict__ Whi, const ushort* __restrict__ Wlo,   // [n][k]
        const float* __restrict__ dinv, ushort* __restrict__ Tp, int M) {
    int wid = threadIdx.x >> 6, lane = threadIdx.x & 63;
    int row0 = blockIdx.x * 64 + wid * 16;
    int l15 = lane & 15;
    int rA = row0 + l15;
    int kg = (lane >> 4) * 8;
    f32x4 acc[8] = {};
    #pragma unroll
    for (int g = 0; g < 4; g++) {
        int k0 = g * 32 + kg;
        UB ahi, alo;
        if (F32A) {
            float4 f0 = make_float4(0.f, 0.f, 0.f, 0.f), f1 = f0;
            if (rA < M) {
                f0 = *(const float4*)&Xf[(size_t)rA * 128 + k0];
                f1 = *(const float4*)&Xf[(size_t)rA * 128 + k0 + 4];
            }
            float f[8] = {f0.x, f0.y, f0.z, f0.w, f1.x, f1.y, f1.z, f1.w};
            ushort h[8], l[8];
            #pragma unroll
            for (int j = 0; j < 8; j++) { h[j] = f2b(f[j]); l[j] = f2b(f[j] - b2f(h[j])); }
            ahi.u = uint4v{(uint)h[0] | ((uint)h[1] << 16), (uint)h[2] | ((uint)h[3] << 16),
                           (uint)h[4] | ((uint)h[5] << 16), (uint)h[6] | ((uint)h[7] << 16)};
            alo.u = uint4v{(uint)l[0] | ((uint)l[1] << 16), (uint)l[2] | ((uint)l[3] << 16),
                           (uint)l[4] | ((uint)l[5] << 16), (uint)l[6] | ((uint)l[7] << 16)};
        } else {
            ahi.u = *(const uint4v*)&Xhi[(size_t)rA * 128 + k0];
            alo.u = *(const uint4v*)&Xlo[(size_t)rA * 128 + k0];
        }
        #pragma unroll
        for (int n = 0; n < 8; n++) {
            UB bhi, blo;
            bhi.u = *(const uint4v*)&Whi[(n * 16 + l15) * 128 + k0];
            blo.u = *(const uint4v*)&Wlo[(n * 16 + l15) * 128 + k0];
            acc[n] = __builtin_amdgcn_mfma_f32_16x16x32_bf16(ahi.b, bhi.b, acc[n], 0, 0, 0);
            acc[n] = __builtin_amdgcn_mfma_f32_16x16x32_bf16(ahi.b, blo.b, acc[n], 0, 0, 0);
            acc[n] = __builtin_amdgcn_mfma_f32_16x16x32_bf16(alo.b, bhi.b, acc[n], 0, 0, 0);
        }
    }
    int rbase = row0 + (lane >> 4) * 4;
    #pragma unroll
    for (int r = 0; r < 4; r++) {
        int row = rbase + r;
        if (row < M) {
            float dv = dinv[row];
            #pragma unroll
            for (int n = 0; n < 8; n++)
                Tp[(size_t)row * 128 + n * 16 + l15] = f2b(dv * acc[n][r]);
        }
    }
}

// ---------------- aggregate: out[d] = relu(b + dinv[d]*(T'[d] + sum T'[src])), split hi/lo ----------

__global__ __launch_bounds__(256) void aggregate_k(const ushort* __restrict__ Tp,
        const int* __restrict__ idxb, const int* __restrict__ off, const int* __restrict__ deg,
        const float* __restrict__ dinv, const float* __restrict__ bias,
        ushort* __restrict__ ohi, ushort* __restrict__ olo, int N) {
    int w = threadIdx.x >> 6, lane = threadIdx.x & 63;
    int d = blockIdx.x * 4 + w;
    int half = lane >> 5, l31 = lane & 31;
    int dim4 = l31 * 4;
    if (d >= N) {   // pad rows: zero (GEMM A-operand reads them)
        if (half == 0) *(ushort4*)&ohi[(size_t)d * 128 + dim4] = make_ushort4(0, 0, 0, 0);
        else           *(ushort4*)&olo[(size_t)d * 128 + dim4] = make_ushort4(0, 0, 0, 0);
        return;
    }
    float a0 = 0.f, a1 = 0.f, a2 = 0.f, a3 = 0.f;
    int o = off[d], n = deg[d];
    int cnt = n + 1;   // position 0 = self
    for (int c = 0; c < cnt; c += 64) {
        int p = c + lane;
        int id = 0;
        if (p < cnt) id = (p == 0) ? d : idxb[o + p - 1];
        int m = min(64, cnt - c);
        int lim = (m - half + 1) >> 1;   // edges this half processes
        int jj = 0;
        for (; jj + 3 < lim; jj += 4) {
            int s0 = __shfl(id, (jj + 0) * 2 + half);
            int s1 = __shfl(id, (jj + 1) * 2 + half);
            int s2 = __shfl(id, (jj + 2) * 2 + half);
            int s3 = __shfl(id, (jj + 3) * 2 + half);
            ushort4 v0 = *(const ushort4*)&Tp[(size_t)s0 * 128 + dim4];
            ushort4 v1 = *(const ushort4*)&Tp[(size_t)s1 * 128 + dim4];
            ushort4 v2 = *(const ushort4*)&Tp[(size_t)s2 * 128 + dim4];
            ushort4 v3 = *(const ushort4*)&Tp[(size_t)s3 * 128 + dim4];
            a0 += b2f(v0.x); a1 += b2f(v0.y); a2 += b2f(v0.z); a3 += b2f(v0.w);
            a0 += b2f(v1.x); a1 += b2f(v1.y); a2 += b2f(v1.z); a3 += b2f(v1.w);
            a0 += b2f(v2.x); a1 += b2f(v2.y); a2 += b2f(v2.z); a3 += b2f(v2.w);
            a0 += b2f(v3.x); a1 += b2f(v3.y); a2 += b2f(v3.z); a3 += b2f(v3.w);
        }
        for (; jj < lim; jj++) {
            int s = __shfl(id, jj * 2 + half);
            ushort4 v = *(const ushort4*)&Tp[(size_t)s * 128 + dim4];
            a0 += b2f(v.x); a1 += b2f(v.y); a2 += b2f(v.z); a3 += b2f(v.w);
        }
    }
    a0 += __shfl_xor(a0, 32); a1 += __shfl_xor(a1, 32);
    a2 += __shfl_xor(a2, 32); a3 += __shfl_xor(a3, 32);
    float di = dinv[d];
    float4 bv = *(const float4*)&bias[dim4];
    float f0 = fmaxf(di * a0 + bv.x, 0.f);
    float f1 = fmaxf(di * a1 + bv.y, 0.f);
    float f2 = fmaxf(di * a2 + bv.z, 0.f);
    float f3 = fmaxf(di * a3 + bv.w, 0.f);
    ushort h0 = f2b(f0), h1 = f2b(f1), h2 = f2b(f2), h3 = f2b(f3);
    if (half == 0) {
        *(ushort4*)&ohi[(size_t)d * 128 + dim4] = make_ushort4(h0, h1, h2, h3);
    } else {
        *(ushort4*)&olo[(size_t)d * 128 + dim4] =
            make_ushort4(f2b(f0 - b2f(h0)), f2b(f1 - b2f(h1)), f2b(f2 - b2f(h2)), f2b(f3 - b2f(h3)));
    }
}

// ---------------- loss heads ----------------

__device__ __forceinline__ float wred64(float x) {
    #pragma unroll
    for (int o = 32; o > 0; o >>= 1) x += __shfl_xor(x, o);
    return x;
}
__device__ __forceinline__ float sp100(float z) {   // min(softplus(z),100)
    float sp = (z > 0.f) ? (z + log1pf(expf(-z))) : log1pf(expf(z));
    return fminf(sp, 100.f);
}
__device__ __forceinline__ float2 ldf2(const ushort* hi, const ushort* lo, size_t idx) {
    ushort2 h = *(const ushort2*)&hi[idx];
    ushort2 l = *(const ushort2*)&lo[idx];
    float2 r;
    r.x = b2f(h.x) + b2f(l.x);
    r.y = b2f(h.y) + b2f(l.y);
    return r;
}

__global__ __launch_bounds__(256) void loss1_k(const ushort* __restrict__ Xhi, const ushort* __restrict__ Xlo,
        const int* __restrict__ user, const int* __restrict__ item,
        const float* __restrict__ Wp, const float* __restrict__ Wdu, const float* __restrict__ Wdi,
        float* __restrict__ zp, float* __restrict__ zu, float* __restrict__ zi, int B) {
    int lane = threadIdx.x & 63;
    int wid = (blockIdx.x * blockDim.x + threadIdx.x) >> 6;
    int nw = (gridDim.x * blockDim.x) >> 6;
    int k = lane * 2;
    float2 wpu = *(const float2*)&Wp[k];
    float2 wpi = *(const float2*)&Wp[256 + k];
    float2 wdu = *(const float2*)&Wdu[k];
    float2 wdi = *(const float2*)&Wdi[k];
    for (int s = wid; s < B; s += nw) {
        int u = user[s];
        int it = item[s] + NUM_USER;
        float2 uv = ldf2(Xhi, Xlo, (size_t)u * 128 + k);
        float2 iv = ldf2(Xhi, Xlo, (size_t)it * 128 + k);
        float p_ = uv.x * wpu.x + uv.y * wpu.y + iv.x * wpi.x + iv.y * wpi.y;
        float uu = uv.x * wdu.x + uv.y * wdu.y;
        float ii = iv.x * wdi.x + iv.y * wdi.y;
        p_ = wred64(p_); uu = wred64(uu); ii = wred64(ii);
        if (lane == 0) { zp[s] = p_; zu[s] = uu; zi[s] = ii; }
    }
}

__global__ __launch_bounds__(256) void loss2_k(const ushort* __restrict__ Xhi, const ushort* __restrict__ Xlo,
        const int* __restrict__ user, const int* __restrict__ item, const int* __restrict__ labels,
        const float* __restrict__ Wp, const float* __restrict__ bp,
        const float* __restrict__ Wdu, const float* __restrict__ bdu,
        const float* __restrict__ Wdi, const float* __restrict__ bdi,
        const float* __restrict__ zp, const float* __restrict__ zu, const float* __restrict__ zi,
        float* __restrict__ acc, int is_target, int B) {
    __shared__ float part[3][4];
    int tid = threadIdx.x;
    int lane = tid & 63, w = tid >> 6;
    int wid = (blockIdx.x * blockDim.x + tid) >> 6;
    int nw = (gridDim.x * blockDim.x) >> 6;
    int k = lane * 2;
    float2 wpu = *(const float2*)&Wp[128 + k];
    float2 wpi = *(const float2*)&Wp[384 + k];
    float2 wdu = *(const float2*)&Wdu[128 + k];
    float2 wdi = *(const float2*)&Wdi[128 + k];
    float lp = 0.f, lu = 0.f, li = 0.f;
    for (int s = wid; s < B; s += nw) {
        int u = user[s];
        int it = item[s] + NUM_USER;
        float2 uv = ldf2(Xhi, Xlo, (size_t)u * 128 + k);
        float2 iv = ldf2(Xhi, Xlo, (size_t)it * 128 + k);
        float p_ = uv.x * wpu.x + uv.y * wpu.y + iv.x * wpi.x + iv.y * wpi.y;
        float uu = uv.x * wdu.x + uv.y * wdu.y;
        float ii = iv.x * wdi.x + iv.y * wdi.y;
        p_ = wred64(p_); uu = wred64(uu); ii = wred64(ii);
        if (lane == 0) {
            float zpt = zp[s] + p_ + bp[0];
            float zut = zu[s] + uu + bdu[0];
            float zit = zi[s] + ii + bdi[0];
            lp += labels[s] ? sp100(-zpt) : sp100(zpt);
            lu += is_target ? sp100(-zut) : sp100(zut);
            li += is_target ? sp100(-zit) : sp100(zit);
        }
    }
    if (lane == 0) { part[0][w] = lp; part[1][w] = lu; part[2][w] = li; }
    __syncthreads();
    if (tid == 0) {
        float s0 = 0.f, s1 = 0.f, s2 = 0.f;
        for (int j = 0; j < 4; j++) { s0 += part[0][j]; s1 += part[1][j]; s2 += part[2][j]; }
        atomicAdd(&acc[is_target ? 1 : 0], s0);
        atomicAdd(&acc[2], s1);
        atomicAdd(&acc[3], s2);
    }
}

__global__ void fin_k(const float* __restrict__ acc, float* __restrict__ out, int B) {
    float invB = 1.f / (float)B;
    out[0] = acc[0] * invB + acc[1] * invB + 0.1f * ((acc[2] + acc[3]) * (0.5f * invB));
}

// ---------------- orchestration ----------------

extern "C" void kernel_launch(void* const* d_in, const int* in_sizes, int n_in,
                              void* d_out, int out_size, void* d_ws, size_t ws_size,
                              hipStream_t stream) {
    const float* feats[2] = {(const float*)d_in[0], (const float*)d_in[1]};
    const int* adj[2]    = {(const int*)d_in[2], (const int*)d_in[3]};
    const int* user[2]   = {(const int*)d_in[4], (const int*)d_in[7]};
    const int* item[2]   = {(const int*)d_in[5], (const int*)d_in[8]};
    const int* labels[2] = {(const int*)d_in[6], (const int*)d_in[9]};
    const float* Wl[2] = {(const float*)d_in[10], (const float*)d_in[12]};
    const float* bl[2] = {(const float*)d_in[11], (const float*)d_in[13]};
    const float* Wp  = (const float*)d_in[14];
    const float* bp  = (const float*)d_in[15];
    const float* Wdu = (const float*)d_in[16];
    const float* bdu = (const float*)d_in[17];
    const float* Wdi = (const float*)d_in[18];
    const float* bdi = (const float*)d_in[19];

    const int E = in_sizes[2] / 2;
    const int B = in_sizes[4];
    const int N = N_NODES;

    char* w = (char*)d_ws;
    ushort* Tp   = (ushort*)w; w += (size_t)MPAD * 128 * 2;
    ushort* Fhi  = (ushort*)w; w += (size_t)MPAD * 128 * 2;
    ushort* Flo  = (ushort*)w; w += (size_t)MPAD * 128 * 2;
    ushort* W1h  = (ushort*)w; w += 16384 * 2;
    ushort* W1l  = (ushort*)w; w += 16384 * 2;
    ushort* W2h  = (ushort*)w; w += 16384 * 2;
    ushort* W2l  = (ushort*)w; w += 16384 * 2;
    int*   deg  = (int*)w;   w += (size_t)N * 4;
    float* dinv = (float*)w; w += (size_t)N * 4;
    int*   off  = (int*)w;   w += (size_t)N * 4;
    int*   idxb = (int*)w;   w += (size_t)E * 4;
    unsigned int* stg = (unsigned int*)w; w += (size_t)E * 4;
    int*   tbl  = (int*)w;   w += (size_t)512 * NBUCK * 4;   // up to 512 hist blocks
    int*   bbase = (int*)w;  w += NBUCK * 4;
    int*   bcnt  = (int*)w;  w += NBUCK * 4;
    float* zp   = (float*)w; w += (size_t)B * 4;
    float* zu   = (float*)w; w += (size_t)B * 4;
    float* zi   = (float*)w; w += (size_t)B * 4;
    float* acc  = (float*)w; w += 64;

    hipMemsetAsync(acc, 0, 64, stream);
    convw_k<<<64, 256, 0, stream>>>(Wl[0], W1h, W1l);
    convw_k<<<64, 256, 0, stream>>>(Wl[1], W2h, W2l);

    int nbE = (E + EPB - 1) / EPB;               // hist/bin blocks
    int nbB = (N + NPB - 1) / NPB;               // csr blocks (215)
    int gMM = MPAD / 64, gAG = MPAD / 4;
    for (int dom = 0; dom < 2; dom++) {
        const int* srcp = adj[dom];
        const int* dstp = adj[dom] + E;

        hist_k<<<nbE, 256, 0, stream>>>(dstp, tbl, E);
        scanb_k<<<1, 256, 0, stream>>>(tbl, bbase, bcnt, nbE);
        bin_k<<<nbE, 256, 0, stream>>>(srcp, dstp, tbl, bbase, stg, E);
        csr_k<<<nbB, 256, 0, stream>>>(stg, bbase, bcnt, deg, dinv, off, idxb, N);

        // layer 1 (f32 input feats, split in-register)
        mm_k<true><<<gMM, 256, 0, stream>>>(feats[dom], nullptr, nullptr, W1h, W1l, dinv, Tp, N);
        aggregate_k<<<gAG, 256, 0, stream>>>(Tp, idxb, off, deg, dinv, bl[0], Fhi, Flo, N);
        loss1_k<<<512, 256, 0, stream>>>(Fhi, Flo, user[dom], item[dom], Wp, Wdu, Wdi, zp, zu, zi, B);

        // layer 2 (bf16 hi/lo input)
        mm_k<false><<<gMM, 256, 0, stream>>>(nullptr, Fhi, Flo, W2h, W2l, dinv, Tp, N);
        aggregate_k<<<gAG, 256, 0, stream>>>(Tp, idxb, off, deg, dinv, bl[1], Fhi, Flo, N);
        loss2_k<<<512, 256, 0, stream>>>(Fhi, Flo, user[dom], item[dom], labels[dom],
                                         Wp, bp, Wdu, bdu, Wdi, bdi,
                                         zp, zu, zi, acc, dom, B);
    }
    fin_k<<<1, 1, 0, stream>>>(acc, (float*)d_out, B);
}

// Round 5
// 770.250 us; speedup vs baseline: 2.6161x; 1.3810x over previous
//
#include <hip/hip_runtime.h>

#define N_NODES 110000
#define NUM_USER 60000
#define MPAD 110016        // N_NODES padded to 64-row GEMM tiles
#define BSHIFT 9           // bucket = dst >> 9  (512 nodes per bucket)
#define NBUCK 256
#define NPB 512            // nodes per bucket
#define EPB 8192           // edges per block in hist/bin
#define CAP 9216           // per-bucket edge capacity in csr_k LDS

typedef __attribute__((ext_vector_type(8))) __bf16 bf16x8;
typedef __attribute__((ext_vector_type(4))) float f32x4;
typedef __attribute__((ext_vector_type(4))) unsigned int uint4v;

union UB { uint4v u; bf16x8 b; };

__device__ __forceinline__ unsigned short f2b(float f) {   // f32 -> bf16 RNE
    unsigned int u = __float_as_uint(f);
    unsigned int r = (u + 0x7FFFu + ((u >> 16) & 1u)) >> 16;
    return (unsigned short)r;
}
__device__ __forceinline__ float b2f(unsigned short h) {
    return __uint_as_float(((unsigned int)h) << 16);
}

// ---------------- bucket-sort CSR build ----------------

__global__ __launch_bounds__(256) void hist_k(const int* __restrict__ dst, int* __restrict__ tbl, int E) {
    __shared__ int h[NBUCK];
    int tid = threadIdx.x, b = blockIdx.x;
    h[tid] = 0;
    __syncthreads();
    int base = b * EPB, end = min(base + EPB, E);
    for (int i = base + tid * 4; i + 3 < end; i += 1024) {
        int4 d = *(const int4*)&dst[i];
        atomicAdd(&h[d.x >> BSHIFT], 1); atomicAdd(&h[d.y >> BSHIFT], 1);
        atomicAdd(&h[d.z >> BSHIFT], 1); atomicAdd(&h[d.w >> BSHIFT], 1);
    }
    __syncthreads();
    tbl[b * NBUCK + tid] = h[tid];
}

__global__ __launch_bounds__(256) void scanb_k(int* __restrict__ tbl, int* __restrict__ bbase,
                                               int* __restrict__ bcnt, int nblocks) {
    __shared__ int sh[NBUCK];
    int t = threadIdx.x;
    int s = 0;
    for (int blk = 0; blk < nblocks; blk++) {
        int v = tbl[blk * NBUCK + t];
        tbl[blk * NBUCK + t] = s;
        s += v;
    }
    bcnt[t] = s;
    sh[t] = s;
    __syncthreads();
    for (int o = 1; o < NBUCK; o <<= 1) {
        int v = (t >= o) ? sh[t - o] : 0;
        __syncthreads();
        sh[t] += v;
        __syncthreads();
    }
    bbase[t] = sh[t] - s;   // exclusive
}

__global__ __launch_bounds__(256) void bin_k(const int* __restrict__ src, const int* __restrict__ dst,
        const int* __restrict__ tbl, const int* __restrict__ bbase,
        unsigned int* __restrict__ stg, int E) {
    __shared__ int lcur[NBUCK];
    int tid = threadIdx.x, b = blockIdx.x;
    lcur[tid] = bbase[tid] + tbl[b * NBUCK + tid];
    __syncthreads();
    int base = b * EPB, end = min(base + EPB, E);
    for (int i = base + tid * 4; i + 3 < end; i += 1024) {
        int4 s = *(const int4*)&src[i];
        int4 d = *(const int4*)&dst[i];
        int p;
        p = atomicAdd(&lcur[d.x >> BSHIFT], 1); stg[p] = (unsigned)s.x | ((unsigned)(d.x & (NPB - 1)) << 17);
        p = atomicAdd(&lcur[d.y >> BSHIFT], 1); stg[p] = (unsigned)s.y | ((unsigned)(d.y & (NPB - 1)) << 17);
        p = atomicAdd(&lcur[d.z >> BSHIFT], 1); stg[p] = (unsigned)s.z | ((unsigned)(d.z & (NPB - 1)) << 17);
        p = atomicAdd(&lcur[d.w >> BSHIFT], 1); stg[p] = (unsigned)s.w | ((unsigned)(d.w & (NPB - 1)) << 17);
    }
}

__global__ __launch_bounds__(256) void csr_k(const unsigned int* __restrict__ stg,
        const int* __restrict__ bbase, const int* __restrict__ bcnt,
        int* __restrict__ deg, float* __restrict__ dinv, int* __restrict__ off,
        int* __restrict__ idxb, int N) {
    __shared__ int ldeg[NPB];
    __shared__ int lcur[NPB];
    __shared__ int shp[256];
    __shared__ unsigned int lidx[CAP];
    int tid = threadIdx.x, b = blockIdx.x;
    int node0 = b * NPB;
    int base = bbase[b], cnt = bcnt[b];
    ldeg[tid] = 0; ldeg[tid + 256] = 0;
    __syncthreads();
    for (int i = tid; i < cnt; i += 256)
        atomicAdd(&ldeg[stg[base + i] >> 17], 1);
    __syncthreads();
    int a0 = ldeg[2 * tid], a1 = ldeg[2 * tid + 1];
    shp[tid] = a0 + a1;
    __syncthreads();
    for (int o = 1; o < 256; o <<= 1) {
        int v = (tid >= o) ? shp[tid - o] : 0;
        __syncthreads();
        shp[tid] += v;
        __syncthreads();
    }
    int excl = shp[tid] - a0 - a1;
    lcur[2 * tid] = excl;
    lcur[2 * tid + 1] = excl + a0;
    int n0 = node0 + 2 * tid;
    if (n0 < N)     { deg[n0] = a0;     dinv[n0] = rsqrtf(a0 + 1.f);     off[n0] = base + excl; }
    if (n0 + 1 < N) { deg[n0 + 1] = a1; dinv[n0 + 1] = rsqrtf(a1 + 1.f); off[n0 + 1] = base + excl + a0; }
    __syncthreads();
    for (int i = tid; i < cnt; i += 256) {
        unsigned e = stg[base + i];
        int p = atomicAdd(&lcur[e >> 17], 1);
        if (p < CAP) lidx[p] = e & 0x1FFFFu;
    }
    __syncthreads();
    for (int i = tid; i < cnt; i += 256)
        idxb[base + i] = (int)lidx[i];
}

// ---------------- weights: W (128x128, [k][n]) -> transposed bf16 hi/lo ([n][k]) ----------------

__global__ __launch_bounds__(256) void convw_k(const float* __restrict__ W,
        ushort* __restrict__ hi, ushort* __restrict__ lo) {
    int i = blockIdx.x * blockDim.x + threadIdx.x;   // 16384 total
    int k = i >> 7, n = i & 127;
    float w = W[i];
    ushort h = f2b(w);
    hi[(n << 7) | k] = h;
    lo[(n << 7) | k] = f2b(w - b2f(h));
}

// ---------------- GEMM: T'(bf16, Mx128) = dinv[row] * (A @ W), split-bf16 MFMA ----------------

template<bool F32A>
__global__ __launch_bounds__(256) void mm_k(const float* __restrict__ Xf,
        const ushort* __restrict__ Xhi, const ushort* __restrict__ Xlo,
        const ushort* __restrict__ Whi, const ushort* __restrict__ Wlo,   // [n][k]
        const float* __restrict__ dinv, ushort* __restrict__ Tp, int M) {
    int wid = threadIdx.x >> 6, lane = threadIdx.x & 63;
    int row0 = blockIdx.x * 64 + wid * 16;
    int l15 = lane & 15;
    int rA = row0 + l15;
    int kg = (lane >> 4) * 8;
    f32x4 acc[8] = {};
    #pragma unroll
    for (int g = 0; g < 4; g++) {
        int k0 = g * 32 + kg;
        UB ahi, alo;
        if (F32A) {
            float4 f0 = make_float4(0.f, 0.f, 0.f, 0.f), f1 = f0;
            if (rA < M) {
                f0 = *(const float4*)&Xf[(size_t)rA * 128 + k0];
                f1 = *(const float4*)&Xf[(size_t)rA * 128 + k0 + 4];
            }
            float f[8] = {f0.x, f0.y, f0.z, f0.w, f1.x, f1.y, f1.z, f1.w};
            ushort h[8], l[8];
            #pragma unroll
            for (int j = 0; j < 8; j++) { h[j] = f2b(f[j]); l[j] = f2b(f[j] - b2f(h[j])); }
            ahi.u = uint4v{(uint)h[0] | ((uint)h[1] << 16), (uint)h[2] | ((uint)h[3] << 16),
                           (uint)h[4] | ((uint)h[5] << 16), (uint)h[6] | ((uint)h[7] << 16)};
            alo.u = uint4v{(uint)l[0] | ((uint)l[1] << 16), (uint)l[2] | ((uint)l[3] << 16),
                           (uint)l[4] | ((uint)l[5] << 16), (uint)l[6] | ((uint)l[7] << 16)};
        } else {
            ahi.u = *(const uint4v*)&Xhi[(size_t)rA * 128 + k0];
            alo.u = *(const uint4v*)&Xlo[(size_t)rA * 128 + k0];
        }
        #pragma unroll
        for (int n = 0; n < 8; n++) {
            UB bhi, blo;
            bhi.u = *(const uint4v*)&Whi[(n * 16 + l15) * 128 + k0];
            blo.u = *(const uint4v*)&Wlo[(n * 16 + l15) * 128 + k0];
            acc[n] = __builtin_amdgcn_mfma_f32_16x16x32_bf16(ahi.b, bhi.b, acc[n], 0, 0, 0);
            acc[n] = __builtin_amdgcn_mfma_f32_16x16x32_bf16(ahi.b, blo.b, acc[n], 0, 0, 0);
            acc[n] = __builtin_amdgcn_mfma_f32_16x16x32_bf16(alo.b, bhi.b, acc[n], 0, 0, 0);
        }
    }
    int rbase = row0 + (lane >> 4) * 4;
    #pragma unroll
    for (int r = 0; r < 4; r++) {
        int row = rbase + r;
        if (row < M) {
            float dv = dinv[row];
            #pragma unroll
            for (int n = 0; n < 8; n++)
                Tp[(size_t)row * 128 + n * 16 + l15] = f2b(dv * acc[n][r]);
        }
    }
}

// ---------------- aggregate + fused per-node head dots ----------------
// out[d] = relu(b + dinv[d]*(T'[d] + sum T'[src])), hi/lo split
// nd[d] = (f.Wp_user, f.Wp_item, f.Wdu, f.Wdi) for this layer's weight slices

__global__ __launch_bounds__(256) void aggregate_k(const ushort* __restrict__ Tp,
        const int* __restrict__ idxb, const int* __restrict__ off, const int* __restrict__ deg,
        const float* __restrict__ dinv, const float* __restrict__ bias,
        const float* __restrict__ Wp, const float* __restrict__ Wdu, const float* __restrict__ Wdi,
        int loff,   // 0 for layer 1, 128 for layer 2
        float4* __restrict__ nd,
        ushort* __restrict__ ohi, ushort* __restrict__ olo, int N) {
    int w = threadIdx.x >> 6, lane = threadIdx.x & 63;
    int d = blockIdx.x * 4 + w;
    int half = lane >> 5, l31 = lane & 31;
    int dim4 = l31 * 4;
    if (d >= N) {   // pad rows: zero (GEMM A-operand reads them)
        if (half == 0) *(ushort4*)&ohi[(size_t)d * 128 + dim4] = make_ushort4(0, 0, 0, 0);
        else           *(ushort4*)&olo[(size_t)d * 128 + dim4] = make_ushort4(0, 0, 0, 0);
        return;
    }
    float a0 = 0.f, a1 = 0.f, a2 = 0.f, a3 = 0.f;
    int o = off[d], n = deg[d];
    int cnt = n + 1;   // position 0 = self
    for (int c = 0; c < cnt; c += 64) {
        int p = c + lane;
        int id = 0;
        if (p < cnt) id = (p == 0) ? d : idxb[o + p - 1];
        int m = min(64, cnt - c);
        int lim = (m - half + 1) >> 1;   // edges this half processes
        int jj = 0;
        for (; jj + 3 < lim; jj += 4) {
            int s0 = __shfl(id, (jj + 0) * 2 + half);
            int s1 = __shfl(id, (jj + 1) * 2 + half);
            int s2 = __shfl(id, (jj + 2) * 2 + half);
            int s3 = __shfl(id, (jj + 3) * 2 + half);
            ushort4 v0 = *(const ushort4*)&Tp[(size_t)s0 * 128 + dim4];
            ushort4 v1 = *(const ushort4*)&Tp[(size_t)s1 * 128 + dim4];
            ushort4 v2 = *(const ushort4*)&Tp[(size_t)s2 * 128 + dim4];
            ushort4 v3 = *(const ushort4*)&Tp[(size_t)s3 * 128 + dim4];
            a0 += b2f(v0.x); a1 += b2f(v0.y); a2 += b2f(v0.z); a3 += b2f(v0.w);
            a0 += b2f(v1.x); a1 += b2f(v1.y); a2 += b2f(v1.z); a3 += b2f(v1.w);
            a0 += b2f(v2.x); a1 += b2f(v2.y); a2 += b2f(v2.z); a3 += b2f(v2.w);
            a0 += b2f(v3.x); a1 += b2f(v3.y); a2 += b2f(v3.z); a3 += b2f(v3.w);
        }
        for (; jj < lim; jj++) {
            int s = __shfl(id, jj * 2 + half);
            ushort4 v = *(const ushort4*)&Tp[(size_t)s * 128 + dim4];
            a0 += b2f(v.x); a1 += b2f(v.y); a2 += b2f(v.z); a3 += b2f(v.w);
        }
    }
    a0 += __shfl_xor(a0, 32); a1 += __shfl_xor(a1, 32);
    a2 += __shfl_xor(a2, 32); a3 += __shfl_xor(a3, 32);
    float di = dinv[d];
    float4 bv = *(const float4*)&bias[dim4];
    float f0 = fmaxf(di * a0 + bv.x, 0.f);
    float f1 = fmaxf(di * a1 + bv.y, 0.f);
    float f2 = fmaxf(di * a2 + bv.z, 0.f);
    float f3 = fmaxf(di * a3 + bv.w, 0.f);
    ushort h0 = f2b(f0), h1 = f2b(f1), h2 = f2b(f2), h3 = f2b(f3);
    if (half == 0) {
        *(ushort4*)&ohi[(size_t)d * 128 + dim4] = make_ushort4(h0, h1, h2, h3);
    } else {
        *(ushort4*)&olo[(size_t)d * 128 + dim4] =
            make_ushort4(f2b(f0 - b2f(h0)), f2b(f1 - b2f(h1)), f2b(f2 - b2f(h2)), f2b(f3 - b2f(h3)));
    }
    // fused per-node head dots (both halves compute identical sums; lane 0 writes)
    float4 wu  = *(const float4*)&Wp[loff + dim4];
    float4 wi  = *(const float4*)&Wp[256 + loff + dim4];
    float4 wdu = *(const float4*)&Wdu[loff + dim4];
    float4 wdi = *(const float4*)&Wdi[loff + dim4];
    float du  = f0 * wu.x  + f1 * wu.y  + f2 * wu.z  + f3 * wu.w;
    float dit = f0 * wi.x  + f1 * wi.y  + f2 * wi.z  + f3 * wi.w;
    float ddu = f0 * wdu.x + f1 * wdu.y + f2 * wdu.z + f3 * wdu.w;
    float ddi = f0 * wdi.x + f1 * wdi.y + f2 * wdi.z + f3 * wdi.w;
    #pragma unroll
    for (int oo = 16; oo > 0; oo >>= 1) {
        du  += __shfl_xor(du, oo);
        dit += __shfl_xor(dit, oo);
        ddu += __shfl_xor(ddu, oo);
        ddi += __shfl_xor(ddi, oo);
    }
    if (lane == 0) nd[d] = make_float4(du, dit, ddu, ddi);
}

// ---------------- loss: per-sample scalar gathers from node-dot tables ----------------

__device__ __forceinline__ float sp100(float z) {   // min(softplus(z),100)
    float sp = (z > 0.f) ? (z + log1pf(expf(-z))) : log1pf(expf(z));
    return fminf(sp, 100.f);
}
__device__ __forceinline__ float wred64(float x) {
    #pragma unroll
    for (int o = 32; o > 0; o >>= 1) x += __shfl_xor(x, o);
    return x;
}

__global__ __launch_bounds__(256) void loss_k(const float4* __restrict__ nd1, const float4* __restrict__ nd2,
        const int* __restrict__ user, const int* __restrict__ item, const int* __restrict__ labels,
        const float* __restrict__ bp, const float* __restrict__ bdu, const float* __restrict__ bdi,
        float* __restrict__ acc, int is_target, int B) {
    __shared__ float sh[3][4];
    int gtid = blockIdx.x * blockDim.x + threadIdx.x;
    int nth = gridDim.x * blockDim.x;
    float bpv = bp[0], bduv = bdu[0], bdiv = bdi[0];
    float lp = 0.f, lu = 0.f, li = 0.f;
    for (int s = gtid; s < B; s += nth) {
        int u = user[s];
        int it = item[s] + NUM_USER;
        float4 a = nd1[u], b = nd2[u], c = nd1[it], dd = nd2[it];
        float zp = a.x + b.x + c.y + dd.y + bpv;
        float zu = a.z + b.z + bduv;
        float zi = c.w + dd.w + bdiv;
        lp += labels[s] ? sp100(-zp) : sp100(zp);
        lu += is_target ? sp100(-zu) : sp100(zu);
        li += is_target ? sp100(-zi) : sp100(zi);
    }
    lp = wred64(lp); lu = wred64(lu); li = wred64(li);
    int lane = threadIdx.x & 63, w = threadIdx.x >> 6;
    if (lane == 0) { sh[0][w] = lp; sh[1][w] = lu; sh[2][w] = li; }
    __syncthreads();
    if (threadIdx.x == 0) {
        float s0 = 0.f, s1 = 0.f, s2 = 0.f;
        for (int j = 0; j < 4; j++) { s0 += sh[0][j]; s1 += sh[1][j]; s2 += sh[2][j]; }
        atomicAdd(&acc[is_target ? 1 : 0], s0);
        atomicAdd(&acc[2], s1);
        atomicAdd(&acc[3], s2);
    }
}

__global__ void fin_k(const float* __restrict__ acc, float* __restrict__ out, int B) {
    float invB = 1.f / (float)B;
    out[0] = acc[0] * invB + acc[1] * invB + 0.1f * ((acc[2] + acc[3]) * (0.5f * invB));
}

// ---------------- orchestration ----------------

extern "C" void kernel_launch(void* const* d_in, const int* in_sizes, int n_in,
                              void* d_out, int out_size, void* d_ws, size_t ws_size,
                              hipStream_t stream) {
    const float* feats[2] = {(const float*)d_in[0], (const float*)d_in[1]};
    const int* adj[2]    = {(const int*)d_in[2], (const int*)d_in[3]};
    const int* user[2]   = {(const int*)d_in[4], (const int*)d_in[7]};
    const int* item[2]   = {(const int*)d_in[5], (const int*)d_in[8]};
    const int* labels[2] = {(const int*)d_in[6], (const int*)d_in[9]};
    const float* Wl[2] = {(const float*)d_in[10], (const float*)d_in[12]};
    const float* bl[2] = {(const float*)d_in[11], (const float*)d_in[13]};
    const float* Wp  = (const float*)d_in[14];
    const float* bp  = (const float*)d_in[15];
    const float* Wdu = (const float*)d_in[16];
    const float* bdu = (const float*)d_in[17];
    const float* Wdi = (const float*)d_in[18];
    const float* bdi = (const float*)d_in[19];

    const int E = in_sizes[2] / 2;
    const int B = in_sizes[4];
    const int N = N_NODES;

    char* w = (char*)d_ws;
    ushort* Tp   = (ushort*)w; w += (size_t)MPAD * 128 * 2;
    ushort* Fhi  = (ushort*)w; w += (size_t)MPAD * 128 * 2;
    ushort* Flo  = (ushort*)w; w += (size_t)MPAD * 128 * 2;
    ushort* W1h  = (ushort*)w; w += 16384 * 2;
    ushort* W1l  = (ushort*)w; w += 16384 * 2;
    ushort* W2h  = (ushort*)w; w += 16384 * 2;
    ushort* W2l  = (ushort*)w; w += 16384 * 2;
    float4* nd1  = (float4*)w; w += (size_t)N * 16;
    float4* nd2  = (float4*)w; w += (size_t)N * 16;
    int*   deg  = (int*)w;   w += (size_t)N * 4;
    float* dinv = (float*)w; w += (size_t)N * 4;
    int*   off  = (int*)w;   w += (size_t)N * 4;
    int*   idxb = (int*)w;   w += (size_t)E * 4;
    unsigned int* stg = (unsigned int*)w; w += (size_t)E * 4;
    int*   tbl  = (int*)w;   w += (size_t)512 * NBUCK * 4;
    int*   bbase = (int*)w;  w += NBUCK * 4;
    int*   bcnt  = (int*)w;  w += NBUCK * 4;
    float* acc  = (float*)w; w += 64;

    hipMemsetAsync(acc, 0, 64, stream);
    convw_k<<<64, 256, 0, stream>>>(Wl[0], W1h, W1l);
    convw_k<<<64, 256, 0, stream>>>(Wl[1], W2h, W2l);

    int nbE = (E + EPB - 1) / EPB;
    int nbB = (N + NPB - 1) / NPB;
    int gMM = MPAD / 64, gAG = MPAD / 4;
    for (int dom = 0; dom < 2; dom++) {
        const int* srcp = adj[dom];
        const int* dstp = adj[dom] + E;

        hist_k<<<nbE, 256, 0, stream>>>(dstp, tbl, E);
        scanb_k<<<1, 256, 0, stream>>>(tbl, bbase, bcnt, nbE);
        bin_k<<<nbE, 256, 0, stream>>>(srcp, dstp, tbl, bbase, stg, E);
        csr_k<<<nbB, 256, 0, stream>>>(stg, bbase, bcnt, deg, dinv, off, idxb, N);

        // layer 1 (f32 input feats, split in-register)
        mm_k<true><<<gMM, 256, 0, stream>>>(feats[dom], nullptr, nullptr, W1h, W1l, dinv, Tp, N);
        aggregate_k<<<gAG, 256, 0, stream>>>(Tp, idxb, off, deg, dinv, bl[0],
                                             Wp, Wdu, Wdi, 0, nd1, Fhi, Flo, N);

        // layer 2 (bf16 hi/lo input)
        mm_k<false><<<gMM, 256, 0, stream>>>(nullptr, Fhi, Flo, W2h, W2l, dinv, Tp, N);
        aggregate_k<<<gAG, 256, 0, stream>>>(Tp, idxb, off, deg, dinv, bl[1],
                                             Wp, Wdu, Wdi, 128, nd2, Fhi, Flo, N);

        loss_k<<<128, 256, 0, stream>>>(nd1, nd2, user[dom], item[dom], labels[dom],
                                        bp, bdu, bdi, acc, dom, B);
    }
    fin_k<<<1, 1, 0, stream>>>(acc, (float*)d_out, B);
}